// Round 1
// baseline (1391.501 us; speedup 1.0000x reference)
//
#include <hip/hip_runtime.h>

// Problem constants (match reference)
#define B_  32
#define S_  2048
#define H_  4096
#define R_  64

typedef __attribute__((ext_vector_type(8))) short  bf16x8;
typedef __attribute__((ext_vector_type(4))) float  f32x4;

// round-half-up fp32 -> bf16 pack of two floats into one u32 (lo in low 16)
__device__ __forceinline__ unsigned pkbf(float a, float b) {
    unsigned ua = __builtin_bit_cast(unsigned, a) + 0x8000u;
    unsigned ub = __builtin_bit_cast(unsigned, b) + 0x8000u;
    return (ua >> 16) | (ub & 0xFFFF0000u);
}

__device__ __forceinline__ bf16x8 cvt8(f32x4 lo, f32x4 hi) {
    union { unsigned u[4]; bf16x8 v; } r;
    r.u[0] = pkbf(lo[0], lo[1]);
    r.u[1] = pkbf(lo[2], lo[3]);
    r.u[2] = pkbf(hi[0], hi[1]);
    r.u[3] = pkbf(hi[2], hi[3]);
    return r.v;
}

// One wave (64 threads) per block. Wave computes a 64(row) x 64(col) output
// tile for one request b: rows s0..s0+63 of x[b], all R=64 adapter rows.
// MFMA 16x16x32 bf16, fragments loaded directly from global (both x and w
// are contiguous in K per lane: 8 consecutive fp32 -> 2 float4 loads).
__global__ __launch_bounds__(64, 1) void multilora_mfma(
        const float* __restrict__ x,      // [B,S,H]
        const int*   __restrict__ ids,    // [B]
        const float* __restrict__ w,      // [NA,R,H]
        float*       __restrict__ out) {  // [B,S,R]
    const int lane = threadIdx.x;         // 0..63
    const int blk  = blockIdx.x;          // 0..1023
    const int b    = blk >> 5;            // 32 blocks per request (S/64)
    const int s0   = (blk & 31) << 6;
    const int a    = ids[b];

    const int l15  = lane & 15;
    const int quad = lane >> 4;           // 0..3
    const int koff = quad * 8;            // k offset within 32-wide k-step

    const float* xbase = x + ((size_t)b * S_ + s0) * H_ + koff;
    const float* wbase = w + ((size_t)a * R_) * H_ + koff;

    const float* ax[4];
    const float* bw[4];
#pragma unroll
    for (int i = 0; i < 4; ++i) {
        ax[i] = xbase + (size_t)(i * 16 + l15) * H_;   // A row = mi*16 + (lane&15)
        bw[i] = wbase + (size_t)(i * 16 + l15) * H_;   // B row (n) = ni*16 + (lane&15)
    }

    f32x4 acc[4][4];
#pragma unroll
    for (int mi = 0; mi < 4; ++mi)
#pragma unroll
        for (int ni = 0; ni < 4; ++ni)
            acc[mi][ni] = (f32x4){0.f, 0.f, 0.f, 0.f};

    // register staging for 1-deep software pipeline
    f32x4 xa[4][2], xb[4][2];
#pragma unroll
    for (int i = 0; i < 4; ++i) {
        xa[i][0] = *(const f32x4*)(ax[i]);
        xa[i][1] = *(const f32x4*)(ax[i] + 4);
        xb[i][0] = *(const f32x4*)(bw[i]);
        xb[i][1] = *(const f32x4*)(bw[i] + 4);
        ax[i] += 32; bw[i] += 32;
    }

    for (int k = 0; k < H_; k += 32) {
        bf16x8 af[4], bfr[4];
#pragma unroll
        for (int i = 0; i < 4; ++i) {
            af[i]  = cvt8(xa[i][0], xa[i][1]);
            bfr[i] = cvt8(xb[i][0], xb[i][1]);
        }
        if (k + 32 < H_) {
#pragma unroll
            for (int i = 0; i < 4; ++i) {
                xa[i][0] = *(const f32x4*)(ax[i]);
                xa[i][1] = *(const f32x4*)(ax[i] + 4);
                xb[i][0] = *(const f32x4*)(bw[i]);
                xb[i][1] = *(const f32x4*)(bw[i] + 4);
                ax[i] += 32; bw[i] += 32;
            }
        }
#pragma unroll
        for (int mi = 0; mi < 4; ++mi)
#pragma unroll
            for (int ni = 0; ni < 4; ++ni)
                acc[mi][ni] = __builtin_amdgcn_mfma_f32_16x16x32_bf16(
                    af[mi], bfr[ni], acc[mi][ni], 0, 0, 0);
    }

    // Epilogue: C/D layout col = lane&15, row = quad*4 + reg  (m89-verified)
    float* ob = out + ((size_t)b * S_ + s0) * R_ + l15;
#pragma unroll
    for (int mi = 0; mi < 4; ++mi) {
#pragma unroll
        for (int i = 0; i < 4; ++i) {
            const int row = mi * 16 + quad * 4 + i;
            float* p = ob + (size_t)row * R_;
#pragma unroll
            for (int ni = 0; ni < 4; ++ni)
                p[ni * 16] = acc[mi][ni][i];
        }
    }
}

extern "C" void kernel_launch(void* const* d_in, const int* in_sizes, int n_in,
                              void* d_out, int out_size, void* d_ws, size_t ws_size,
                              hipStream_t stream) {
    const float* x   = (const float*)d_in[0];
    const int*   ids = (const int*)d_in[1];
    const float* w   = (const float*)d_in[2];
    float*       out = (float*)d_out;

    const int grid = B_ * (S_ / 64);   // 1024 single-wave blocks
    multilora_mfma<<<grid, 64, 0, stream>>>(x, ids, w, out);
}